// Round 1
// baseline (20224.809 us; speedup 1.0000x reference)
//
#include <hip/hip_runtime.h>
#include <math.h>

// ---------------------------------------------------------------------------
// Attention-LSTM decoder (teacher-forced), MI355X round 1: all-fp32 baseline.
//
// Decomposition:
//   P0  k_gather : xembT[t][k][n] = emb_table[text[n][t]][k]   (transposed)
//   loop t in 0..199 (sequential recurrence, 3 kernels/step):
//     S1 k_att   : energy=key.h2, mask, softmax, ctx=att.value  (per-batch WG)
//     S2 k_lstm1 : gates1 = [xemb,ctx,h1] @ W1^T  -> h1,c1      (512 WGs)
//     S3 k_lstm2 : gates2 = [h1,h2] @ W2^T -> h2,c2, store h2   (128 WGs)
//   PC  k_out    : logits = h2c(12800x256) @ W_out^T + b_out    (tiled GEMM)
//
// State layouts are [k][n] (batch-fastest) so per-k wave loads are coalesced
// and the layout is MFMA-migration-ready. h1T/h2T double-buffered across steps
// (other WGs of the same kernel may still read the old value).
//
// ws layout (bytes):
//   0        h1T   [2][1024][64] f32   524288
//   524288   c1T   [1024][64]          262144
//   786432   h2T   [2][128][64]         65536
//   851968   c2T   [128][64]            32768
//   884736   ctxT  [128][64]            32768
//   917504   h2c   [12800][256] f32   13107200   rows m=t*64+n: [h2(128),ctx(128)]
//   14024704 xembT [200][512][64]     26214400
//   total ~40.2 MB
// ---------------------------------------------------------------------------

#define NB    64
#define TENC  500
#define TDEC  200
#define EMBD  512
#define HID   1024
#define KSZ   128
#define VSZ   128
#define VOCAB 10000
#define K1    1664   // EMBD + VSZ + HID
#define K2    1152   // HID + KSZ

__device__ __forceinline__ float sigm(float x) { return 1.0f / (1.0f + __expf(-x)); }
__device__ __forceinline__ float ftanh(float x) {
  float ax = fabsf(x);
  float e  = __expf(2.0f * ax);
  float t  = 1.0f - 2.0f / (e + 1.0f);
  return copysignf(t, x);
}

// ---------------------------------------------------------------- P0: gather
__global__ __launch_bounds__(256) void k_gather(const int* __restrict__ text,
                                                const float* __restrict__ emb,
                                                float* __restrict__ xembT) {
  int t = blockIdx.x;
  __shared__ int tok[NB];
  if (threadIdx.x < NB) tok[threadIdx.x] = text[threadIdx.x * TDEC + t];
  __syncthreads();
  float* dst = xembT + (size_t)t * (EMBD * NB);
  for (int idx = threadIdx.x; idx < EMBD * NB; idx += 256) {
    int k = idx >> 6, n = idx & 63;
    dst[idx] = emb[(size_t)tok[n] * EMBD + k];
  }
}

// ------------------------------------------------------------- S1: attention
__global__ __launch_bounds__(256) void k_att(const float* __restrict__ key,
                                             const float* __restrict__ value,
                                             const int* __restrict__ slen,
                                             const float* __restrict__ h2cur, // [128][64]
                                             float* __restrict__ ctxT,        // [128][64]
                                             float* __restrict__ h2c, int t) {
  int n = blockIdx.x;
  int tid = threadIdx.x;
  __shared__ float h2s[KSZ];
  __shared__ float e[TENC];
  __shared__ float red[256];
  __shared__ float ctxp[VSZ];

  if (tid < KSZ) h2s[tid] = h2cur[tid * NB + n];
  __syncthreads();
  int len = slen[n];

  for (int p = tid; p < TENC; p += 256) {
    float acc = 0.f;
    const float* kr = key + ((size_t)n * TENC + p) * KSZ;
    #pragma unroll 8
    for (int k = 0; k < KSZ; k += 4) {
      float4 kv = *reinterpret_cast<const float4*>(kr + k);
      float4 hv = *reinterpret_cast<const float4*>(h2s + k);
      acc += kv.x * hv.x + kv.y * hv.y + kv.z * hv.z + kv.w * hv.w;
    }
    e[p] = (p >= len) ? -1e9f : acc;
  }
  __syncthreads();

  // max
  float m = -INFINITY;
  for (int p = tid; p < TENC; p += 256) m = fmaxf(m, e[p]);
  red[tid] = m;
  __syncthreads();
  for (int s = 128; s > 0; s >>= 1) {
    if (tid < s) red[tid] = fmaxf(red[tid], red[tid + s]);
    __syncthreads();
  }
  m = red[0];
  __syncthreads();

  // exp + sum
  float ssum = 0.f;
  for (int p = tid; p < TENC; p += 256) {
    float ex = __expf(e[p] - m);
    e[p] = ex;
    ssum += ex;
  }
  red[tid] = ssum;
  __syncthreads();
  for (int s = 128; s > 0; s >>= 1) {
    if (tid < s) red[tid] += red[tid + s];
    __syncthreads();
  }
  float inv = 1.0f / red[0];

  // ctx[v] = inv * sum_p e[p]*value[n][p][v], split p-range over 2 halves
  int v = tid & 127, half = tid >> 7;
  float acc = 0.f;
  int p0 = half * 250, p1 = p0 + 250;
  for (int p = p0; p < p1; ++p)
    acc += e[p] * value[((size_t)n * TENC + p) * VSZ + v];
  acc *= inv;
  if (half == 1) ctxp[v] = acc;
  __syncthreads();
  if (half == 0) {
    float c = acc + ctxp[v];
    ctxT[v * NB + n] = c;
    h2c[((size_t)t * NB + n) * 256 + KSZ + v] = c;
  }
}

// ---------------------------------------------------------------- S2: LSTM1
// grid 512, block 256. WG b: h-dims d0=2b, 2b+1. threads: n=tid&63,
// dsub=(tid>>6)&1, kh=tid>>7 (K split in halves of 832). W rows staged in LDS.
#define LSTM1_ACC(ASRC, KOFF, KLO, KHI)                                        \
  for (int k = (KLO); k < (KHI); k += 4) {                                     \
    const float* ap = (ASRC) + (size_t)(k - (KOFF)) * NB + n;                  \
    float av0 = ap[0], av1 = ap[64], av2 = ap[128], av3 = ap[192];             \
    float4 wi4 = *reinterpret_cast<const float4*>(&Wl[wr + 0][k]);             \
    float4 wf4 = *reinterpret_cast<const float4*>(&Wl[wr + 1][k]);             \
    float4 wg4 = *reinterpret_cast<const float4*>(&Wl[wr + 2][k]);             \
    float4 wo4 = *reinterpret_cast<const float4*>(&Wl[wr + 3][k]);             \
    ai += av0 * wi4.x + av1 * wi4.y + av2 * wi4.z + av3 * wi4.w;               \
    af += av0 * wf4.x + av1 * wf4.y + av2 * wf4.z + av3 * wf4.w;               \
    ag += av0 * wg4.x + av1 * wg4.y + av2 * wg4.z + av3 * wg4.w;               \
    ao += av0 * wo4.x + av1 * wo4.y + av2 * wo4.z + av3 * wo4.w;               \
  }

__global__ __launch_bounds__(256) void k_lstm1(
    const float* __restrict__ xembT, const float* __restrict__ ctxT,
    const float* __restrict__ h1cur, float* __restrict__ h1nxt,
    float* __restrict__ c1T,
    const float* __restrict__ Wih1, const float* __restrict__ Whh1,
    const float* __restrict__ bih1, const float* __restrict__ bhh1, int t) {
  __shared__ float Wl[8][K1];          // 53.2 KB: rows = dsub*4 + gate
  __shared__ float bs[8];
  __shared__ float redp[2][NB][4];
  int tid = threadIdx.x;
  int d0 = blockIdx.x * 2;

  for (int row = 0; row < 8; ++row) {
    int dsub = row >> 2, g = row & 3;
    int r = g * HID + d0 + dsub;
    const float* wi = Wih1 + (size_t)r * 640;
    const float* wh = Whh1 + (size_t)r * HID;
    for (int k = tid; k < K1; k += 256)
      Wl[row][k] = (k < 640) ? wi[k] : wh[k - 640];
    if (tid == row) bs[row] = bih1[r] + bhh1[r];
  }
  __syncthreads();

  int n = tid & 63, dsub = (tid >> 6) & 1, kh = tid >> 7;
  const float* xt = xembT + (size_t)t * (EMBD * NB);
  const int wr = dsub * 4;
  float ai = 0.f, af = 0.f, ag = 0.f, ao = 0.f;

  if (kh == 0) {                         // k in [0,832)
    LSTM1_ACC(xt, 0, 0, 512)             // xemb part (W cols 0..511)
    LSTM1_ACC(ctxT, 512, 512, 640)       // ctx part  (W cols 512..639)
    LSTM1_ACC(h1cur, 640, 640, 832)      // h1 part
  } else {                               // k in [832,1664)
    LSTM1_ACC(h1cur, 640, 832, 1664)
  }

  if (kh == 1) {
    redp[dsub][n][0] = ai; redp[dsub][n][1] = af;
    redp[dsub][n][2] = ag; redp[dsub][n][3] = ao;
  }
  __syncthreads();
  if (kh == 0) {
    ai += redp[dsub][n][0]; af += redp[dsub][n][1];
    ag += redp[dsub][n][2]; ao += redp[dsub][n][3];
    int d = d0 + dsub;
    float I = sigm(ai + bs[wr + 0]);
    float F = sigm(af + bs[wr + 1]);
    float G = ftanh(ag + bs[wr + 2]);
    float O = sigm(ao + bs[wr + 3]);
    float c = F * c1T[d * NB + n] + I * G;
    c1T[d * NB + n] = c;
    h1nxt[d * NB + n] = O * ftanh(c);
  }
}

// ---------------------------------------------------------------- S3: LSTM2
// grid 128 (one h-dim each), block 256: n=tid&63, kh=tid>>6 in 0..3 (288 k ea).
__global__ __launch_bounds__(256) void k_lstm2(
    const float* __restrict__ h1nxt, const float* __restrict__ h2cur,
    float* __restrict__ h2nxt, float* __restrict__ c2T,
    const float* __restrict__ Wih2, const float* __restrict__ Whh2,
    const float* __restrict__ bih2, const float* __restrict__ bhh2,
    float* __restrict__ h2c, int t) {
  __shared__ float Wl[4][K2];          // 18.4 KB
  __shared__ float bs[4];
  __shared__ float redp[3][NB][4];
  int tid = threadIdx.x;
  int d = blockIdx.x;

  for (int g = 0; g < 4; ++g) {
    int r = g * KSZ + d;
    const float* wi = Wih2 + (size_t)r * HID;
    const float* wh = Whh2 + (size_t)r * KSZ;
    for (int k = tid; k < K2; k += 256)
      Wl[g][k] = (k < HID) ? wi[k] : wh[k - HID];
    if (tid == g) bs[g] = bih2[r] + bhh2[r];
  }
  __syncthreads();

  int n = tid & 63, kh = tid >> 6;
  float a0 = 0.f, a1 = 0.f, a2 = 0.f, a3 = 0.f;
  int klo = kh * 288, khi = klo + 288;
  int h1hi = (khi < HID) ? khi : HID;   // segment split at k=1024
  for (int k = klo; k < h1hi; k += 4) {
    const float* ap = h1nxt + (size_t)k * NB + n;
    float av0 = ap[0], av1 = ap[64], av2 = ap[128], av3 = ap[192];
    float4 w04 = *reinterpret_cast<const float4*>(&Wl[0][k]);
    float4 w14 = *reinterpret_cast<const float4*>(&Wl[1][k]);
    float4 w24 = *reinterpret_cast<const float4*>(&Wl[2][k]);
    float4 w34 = *reinterpret_cast<const float4*>(&Wl[3][k]);
    a0 += av0 * w04.x + av1 * w04.y + av2 * w04.z + av3 * w04.w;
    a1 += av0 * w14.x + av1 * w14.y + av2 * w14.z + av3 * w14.w;
    a2 += av0 * w24.x + av1 * w24.y + av2 * w24.z + av3 * w24.w;
    a3 += av0 * w34.x + av1 * w34.y + av2 * w34.z + av3 * w34.w;
  }
  for (int k = (klo > HID ? klo : HID); k < khi; k += 4) {  // h2 segment
    if (khi <= HID) break;
    const float* ap = h2cur + (size_t)(k - HID) * NB + n;
    float av0 = ap[0], av1 = ap[64], av2 = ap[128], av3 = ap[192];
    float4 w04 = *reinterpret_cast<const float4*>(&Wl[0][k]);
    float4 w14 = *reinterpret_cast<const float4*>(&Wl[1][k]);
    float4 w24 = *reinterpret_cast<const float4*>(&Wl[2][k]);
    float4 w34 = *reinterpret_cast<const float4*>(&Wl[3][k]);
    a0 += av0 * w04.x + av1 * w04.y + av2 * w04.z + av3 * w04.w;
    a1 += av0 * w14.x + av1 * w14.y + av2 * w14.z + av3 * w14.w;
    a2 += av0 * w24.x + av1 * w24.y + av2 * w24.z + av3 * w24.w;
    a3 += av0 * w34.x + av1 * w34.y + av2 * w34.z + av3 * w34.w;
  }

  if (kh > 0) {
    redp[kh - 1][n][0] = a0; redp[kh - 1][n][1] = a1;
    redp[kh - 1][n][2] = a2; redp[kh - 1][n][3] = a3;
  }
  __syncthreads();
  if (kh == 0) {
    #pragma unroll
    for (int j = 0; j < 3; ++j) {
      a0 += redp[j][n][0]; a1 += redp[j][n][1];
      a2 += redp[j][n][2]; a3 += redp[j][n][3];
    }
    float I = sigm(a0 + bs[0]);
    float F = sigm(a1 + bs[1]);
    float G = ftanh(a2 + bs[2]);
    float O = sigm(a3 + bs[3]);
    float c = F * c2T[d * NB + n] + I * G;
    c2T[d * NB + n] = c;
    float h = O * ftanh(c);
    h2nxt[d * NB + n] = h;
    h2c[((size_t)t * NB + n) * 256 + d] = h;
  }
}

// ------------------------------------------------------ PC: output projection
// logits(12800 x 10000) = h2c(12800 x 256) @ W_out^T + b_out, tiled 64x64,
// K staged in 64-chunks, 4x4 register blocking. Out layout (n, t, vocab).
__global__ __launch_bounds__(256) void k_out(const float* __restrict__ h2c,
                                             const float* __restrict__ Wout,
                                             const float* __restrict__ bout,
                                             float* __restrict__ out) {
  __shared__ float At[64][68];   // [k][m], stride 68 keeps float4 16B-aligned
  __shared__ float Wt[64][68];   // [k][c]
  int tid = threadIdx.x;
  int c0 = blockIdx.x * 64, m0 = blockIdx.y * 64;
  int tx = tid & 15, ty = tid >> 4;
  float acc[4][4] = {};

  for (int kc = 0; kc < 256; kc += 64) {
    for (int e = tid; e < 64 * 64; e += 256) {
      int row = e >> 6, col = e & 63;
      At[col][row] = h2c[(size_t)(m0 + row) * 256 + kc + col];
      int c = c0 + row;
      Wt[col][row] = (c < VOCAB) ? Wout[(size_t)c * 256 + kc + col] : 0.f;
    }
    __syncthreads();
    #pragma unroll
    for (int k = 0; k < 64; ++k) {
      float4 a4 = *reinterpret_cast<const float4*>(&At[k][ty * 4]);
      float4 w4 = *reinterpret_cast<const float4*>(&Wt[k][tx * 4]);
      acc[0][0] += a4.x * w4.x; acc[0][1] += a4.x * w4.y;
      acc[0][2] += a4.x * w4.z; acc[0][3] += a4.x * w4.w;
      acc[1][0] += a4.y * w4.x; acc[1][1] += a4.y * w4.y;
      acc[1][2] += a4.y * w4.z; acc[1][3] += a4.y * w4.w;
      acc[2][0] += a4.z * w4.x; acc[2][1] += a4.z * w4.y;
      acc[2][2] += a4.z * w4.z; acc[2][3] += a4.z * w4.w;
      acc[3][0] += a4.w * w4.x; acc[3][1] += a4.w * w4.y;
      acc[3][2] += a4.w * w4.z; acc[3][3] += a4.w * w4.w;
    }
    __syncthreads();
  }

  int c = c0 + tx * 4;
  if (c < VOCAB) {                       // VOCAB%4==0 -> whole float4 in/out
    float4 bv = *reinterpret_cast<const float4*>(&bout[c]);
    #pragma unroll
    for (int i = 0; i < 4; ++i) {
      int m = m0 + ty * 4 + i;
      int t = m >> 6, n = m & 63;
      float4 o;
      o.x = acc[i][0] + bv.x; o.y = acc[i][1] + bv.y;
      o.z = acc[i][2] + bv.z; o.w = acc[i][3] + bv.w;
      *reinterpret_cast<float4*>(&out[((size_t)n * TDEC + t) * VOCAB + c]) = o;
    }
  }
}

// ---------------------------------------------------------------------------
extern "C" void kernel_launch(void* const* d_in, const int* in_sizes, int n_in,
                              void* d_out, int out_size, void* d_ws, size_t ws_size,
                              hipStream_t stream) {
  (void)in_sizes; (void)n_in; (void)out_size; (void)ws_size;
  const float* key   = (const float*)d_in[0];
  const float* value = (const float*)d_in[1];
  const int*   slen  = (const int*)d_in[2];
  const int*   text  = (const int*)d_in[3];
  const float* emb   = (const float*)d_in[4];
  const float* Wih1  = (const float*)d_in[5];
  const float* Whh1  = (const float*)d_in[6];
  const float* bih1  = (const float*)d_in[7];
  const float* bhh1  = (const float*)d_in[8];
  const float* Wih2  = (const float*)d_in[9];
  const float* Whh2  = (const float*)d_in[10];
  const float* bih2  = (const float*)d_in[11];
  const float* bhh2  = (const float*)d_in[12];
  const float* Wout  = (const float*)d_in[13];
  const float* bout  = (const float*)d_in[14];
  float* out = (float*)d_out;
  char* ws = (char*)d_ws;

  float* h1T   = (float*)(ws + 0);
  float* c1T   = (float*)(ws + 524288);
  float* h2T   = (float*)(ws + 786432);
  float* c2T   = (float*)(ws + 851968);
  float* ctxT  = (float*)(ws + 884736);
  float* h2c   = (float*)(ws + 917504);
  float* xembT = (float*)(ws + 14024704);

  // zero recurrent state (h1T both buffers, c1T, h2T both, c2T, ctxT)
  hipMemsetAsync(d_ws, 0, 917504, stream);

  k_gather<<<TDEC, 256, 0, stream>>>(text, emb, xembT);

  for (int t = 0; t < TDEC; ++t) {
    const float* h2cur = h2T + (t & 1) * (KSZ * NB);
    float*       h2nxt = h2T + ((t + 1) & 1) * (KSZ * NB);
    const float* h1cur = h1T + (t & 1) * (HID * NB);
    float*       h1nxt = h1T + ((t + 1) & 1) * (HID * NB);
    k_att<<<NB, 256, 0, stream>>>(key, value, slen, h2cur, ctxT, h2c, t);
    k_lstm1<<<512, 256, 0, stream>>>(xembT, ctxT, h1cur, h1nxt, c1T,
                                     Wih1, Whh1, bih1, bhh1, t);
    k_lstm2<<<128, 256, 0, stream>>>(h1nxt, h2cur, h2nxt, c2T,
                                     Wih2, Whh2, bih2, bhh2, h2c, t);
  }

  k_out<<<dim3(157, 200), 256, 0, stream>>>(h2c, Wout, bout, out);
}